// Round 12
// baseline (1286.112 us; speedup 1.0000x reference)
//
#include <hip/hip_runtime.h>
#include <math.h>

#define B_EP 256
#define NT 175
#define NWAYS 20
#define KSHOT 5
#define NKS 100          // N_WAYS * N_SHOTS
#define NQ 75
#define DIM 512
#define NLAYERS 4
#define TAU_INV 10.0f
#define LOGIT_SCALE 5.0f
#define KNEI 5
#define SIMLD 176        // u16 stride for SIM-in-LDS (352B rows: conflict-free)
#define STLD 36          // u16 stride for V k-chunk staging (72B: 16 banks)
#define PALD 520         // u16 stride for Pa rows in LDS

typedef unsigned int u32;
typedef unsigned short u16;
typedef __attribute__((ext_vector_type(8))) short s16x8;   // 8 bf16 in 4 VGPRs
typedef __attribute__((ext_vector_type(4))) float f32x4;

__device__ __forceinline__ float waveReduceSum(float v) {
#pragma unroll
  for (int off = 32; off >= 1; off >>= 1) v += __shfl_xor(v, off);
  return v;
}

__device__ __forceinline__ u32 pack2bf(float a, float b) {
  u32 ua = __float_as_uint(a), ub = __float_as_uint(b);
  ua = (ua + 0x7FFFu + ((ua >> 16) & 1u)) >> 16;
  ub = (ub + 0x7FFFu + ((ub >> 16) & 1u)) >> 16;
  return ua | (ub << 16);
}

__device__ __forceinline__ u16 pack1bf(float a) {
  u32 ua = __float_as_uint(a);
  return (u16)((ua + 0x7FFFu + ((ua >> 16) & 1u)) >> 16);
}

__device__ __forceinline__ float bflo(u32 u) { return __uint_as_float(u << 16); }
__device__ __forceinline__ float bfhi(u32 u) { return __uint_as_float(u & 0xFFFF0000u); }
__device__ __forceinline__ float bf1(u16 h) { return __uint_as_float((u32)h << 16); }

__device__ __forceinline__ float tanh_fast(float x) {
  float e = __expf(2.f * x);
  return 1.f - 2.f * __builtin_amdgcn_rcpf(e + 1.f);
}

__device__ __forceinline__ s16x8 ldfrag(const u16* p) {
  return __builtin_bit_cast(s16x8, *(const uint4*)p);
}

// async global->LDS, 16B per lane. LDS dest = wave-uniform base + lane*16.
__device__ __forceinline__ void gload16(const u16* g, u16* l) {
  __builtin_amdgcn_global_load_lds(
      (const __attribute__((address_space(1))) void*)g,
      (__attribute__((address_space(3))) void*)l, 16, 0, 0);
}

__global__ void init_accum_kernel(float* acc) {
  if (threadIdx.x < 16) acc[threadIdx.x] = 0.f;
}

// f32 -> bf16 (RNE), 8 elems/thread (weights only)
__global__ void cvt_bf16_kernel(const float* __restrict__ in,
                                u16* __restrict__ out, int n8) {
  int t = blockIdx.x * 256 + threadIdx.x;
  if (t >= n8) return;
  const float4* p = (const float4*)(in + (size_t)t * 8);
  float4 a = p[0], b = p[1];
  uint4 r;
  r.x = pack2bf(a.x, a.y);
  r.y = pack2bf(a.z, a.w);
  r.z = pack2bf(b.x, b.y);
  r.w = pack2bf(b.z, b.w);
  *(uint4*)(out + (size_t)t * 8) = r;
}

// l2-normalize rows (512 wide) from f32 input -> bf16 master + bf16 residual.
__global__ void l2n_init_kernel(const float* __restrict__ in,
                                u16* __restrict__ outb,
                                u16* __restrict__ out0b) {
  const size_t row = blockIdx.x;
  const int lane = threadIdx.x;
  const float* src = in + row * DIM;
  float4 a = *(const float4*)(src + 4 * lane);
  float4 b = *(const float4*)(src + 256 + 4 * lane);
  float ss = a.x * a.x + a.y * a.y + a.z * a.z + a.w * a.w +
             b.x * b.x + b.y * b.y + b.z * b.z + b.w * b.w;
  ss = waveReduceSum(ss);
  const float inv = 1.f / fmaxf(sqrtf(ss), 1e-12f);
  a.x *= inv; a.y *= inv; a.z *= inv; a.w *= inv;
  b.x *= inv; b.y *= inv; b.z *= inv; b.w *= inv;
  uint2 pa, pb;
  pa.x = pack2bf(a.x, a.y); pa.y = pack2bf(a.z, a.w);
  pb.x = pack2bf(b.x, b.y); pb.y = pack2bf(b.z, b.w);
  *(uint2*)(outb + row * DIM + 4 * lane) = pa;
  *(uint2*)(outb + row * DIM + 256 + 4 * lane) = pb;
  *(uint2*)(out0b + row * DIM + 4 * lane) = pa;
  *(uint2*)(out0b + row * DIM + 256 + 4 * lane) = pb;
}

// Fused instance-graph front-end: per-episode block (576 thr = 9 waves).
__global__ __launch_bounds__(576) void sim_topk_msg_kernel(
    const u16* __restrict__ VB, u16* __restrict__ MSGB) {
  const int b = blockIdx.x;
  const int tid = threadIdx.x;
  const int wave = tid >> 6, lane = tid & 63;
  __shared__ __align__(16) u16 SIMb[NT * SIMLD];  // 61,600 B
  __shared__ __align__(16) u16 Vst[192 * STLD];   // 13,824 B
  const u16* Vb = VB + (size_t)b * NT * DIM;
  const int it = wave / 3, jt = wave - 3 * (wave / 3);
  for (int i = tid; i < (192 - NT) * STLD; i += 576)
    Vst[NT * STLD + i] = 0;
  f32x4 acc[4][4];
#pragma unroll
  for (int m = 0; m < 4; ++m)
#pragma unroll
    for (int n = 0; n < 4; ++n) acc[m][n] = (f32x4){0.f, 0.f, 0.f, 0.f};
  const int part = lane >> 4;  // 0..3 (k sub-chunk of 8 u16)
  for (int kk = 0; kk < DIM; kk += 32) {
    __syncthreads();
#pragma unroll
    for (int r2 = 0; r2 < 2; ++r2) {
      const int idx = tid + 576 * r2;
      if (idx < NT * 4) {
        const int row = idx >> 2, pp = idx & 3;
        uint4 v = *(const uint4*)(Vb + (size_t)row * DIM + kk + pp * 8);
        *(uint4*)&Vst[row * STLD + pp * 8] = v;
      }
    }
    __syncthreads();
    s16x8 fa[4], fb[4];
#pragma unroll
    for (int m = 0; m < 4; ++m)
      fa[m] = ldfrag(&Vst[(it * 64 + m * 16 + (lane & 15)) * STLD + part * 8]);
#pragma unroll
    for (int n = 0; n < 4; ++n)
      fb[n] = ldfrag(&Vst[(jt * 64 + n * 16 + (lane & 15)) * STLD + part * 8]);
#pragma unroll
    for (int m = 0; m < 4; ++m)
#pragma unroll
      for (int n = 0; n < 4; ++n)
        acc[m][n] = __builtin_amdgcn_mfma_f32_16x16x32_bf16(fa[m], fb[n],
                                                            acc[m][n], 0, 0, 0);
  }
  const int r_ = (lane >> 4) * 4, c_ = lane & 15;
#pragma unroll
  for (int m = 0; m < 4; ++m)
#pragma unroll
    for (int n = 0; n < 4; ++n)
#pragma unroll
      for (int j = 0; j < 4; ++j) {
        int r = it * 64 + m * 16 + r_ + j, c = jt * 64 + n * 16 + c_;
        if (r < NT && c < NT) SIMb[r * SIMLD + c] = pack1bf(acc[m][n][j]);
      }
  __syncthreads();
  for (int row = wave; row < NT; row += 9) {
    u32 pk[3];
#pragma unroll
    for (int t = 0; t < 3; ++t) {
      int j = lane + 64 * t;
      if (j < NT) {
        u32 v = SIMb[row * SIMLD + j];
        u32 key = v ^ ((v >> 15) ? 0xFFFFu : 0x8000u);
        pk[t] = (key << 8) | (u32)(255 - j);
      } else {
        pk[t] = 0u;
      }
    }
    float topv[KNEI];
    int topi[KNEI];
#pragma unroll
    for (int t = 0; t < KNEI; ++t) {
      u32 c = max(pk[0], max(pk[1], pk[2]));
#pragma unroll
      for (int off = 32; off >= 1; off >>= 1)
        c = max(c, (u32)__shfl_xor((int)c, off));
#pragma unroll
      for (int u = 0; u < 3; ++u)
        if (pk[u] == c) pk[u] = 0u;
      const u32 k16 = (c >> 8) & 0xFFFFu;
      const u32 v16 = (k16 & 0x8000u) ? (k16 ^ 0x8000u) : (~k16 & 0xFFFFu);
      topv[t] = bf1((u16)v16);
      topi[t] = 255 - (int)(c & 0xFFu);
    }
    float w[KNEI];
    float wsum = 0.f;
#pragma unroll
    for (int t = 0; t < KNEI; ++t) {
      w[t] = __expf((topv[t] - topv[0]) * TAU_INV);
      wsum += w[t];
    }
    const float invs = 1.f / wsum;
    float a8[8] = {0.f, 0.f, 0.f, 0.f, 0.f, 0.f, 0.f, 0.f};
#pragma unroll
    for (int t = 0; t < KNEI; ++t) {
      uint4 v = *(const uint4*)(Vb + (size_t)topi[t] * DIM + 8 * lane);
      a8[0] += w[t] * bflo(v.x); a8[1] += w[t] * bfhi(v.x);
      a8[2] += w[t] * bflo(v.y); a8[3] += w[t] * bfhi(v.y);
      a8[4] += w[t] * bflo(v.z); a8[5] += w[t] * bfhi(v.z);
      a8[6] += w[t] * bflo(v.w); a8[7] += w[t] * bfhi(v.w);
    }
    uint4 r;
    r.x = pack2bf(a8[0] * invs, a8[1] * invs);
    r.y = pack2bf(a8[2] * invs, a8[3] * invs);
    r.z = pack2bf(a8[4] * invs, a8[5] * invs);
    r.w = pack2bf(a8[6] * invs, a8[7] * invs);
    *(uint4*)(MSGB + ((size_t)b * NT + row) * DIM + 8 * lane) = r;
  }
}

// Fused GNN layer tail, bf16 master:
// XB = bf16(l2n(0.8*(XB + s*tanh(A·W^T + bias)) + 0.2*X0B)).
__global__ __launch_bounds__(512) void gemm_fused_kernel(
    const u16* __restrict__ A, const u16* __restrict__ W,
    const float* __restrict__ bias, const float* __restrict__ scale_ptr,
    u16* __restrict__ XB, const u16* __restrict__ X0B) {
  const int row0 = blockIdx.x * 64;
  const int tid = threadIdx.x, wave = tid >> 6, lane = tid & 63;
  __shared__ __align__(16) u16 smem[64 * 512];  // 64KB; As/Bs then U
  u16* As = smem;          // 64x32 u16 (2048)
  u16* Bs = smem + 2048;   // 512x32 u16 (16384)
  f32x4 acc[4][4];
#pragma unroll
  for (int m = 0; m < 4; ++m)
#pragma unroll
    for (int n = 0; n < 4; ++n) acc[m][n] = (f32x4){0.f, 0.f, 0.f, 0.f};
  const int rsrc = lane >> 2;        // 0..15
  const int ksrc = (lane & 3) * 8;   // 0,8,16,24
  for (int kk = 0; kk < DIM; kk += 32) {
#pragma unroll
    for (int q = 0; q < 4; ++q) {
      const int t = wave * 4 + q;  // 0..31 covers all 512 W rows
      gload16(W + (size_t)(t * 16 + rsrc) * DIM + kk + ksrc, Bs + t * 512);
    }
    if (wave < 4)
      gload16(A + (size_t)(row0 + wave * 16 + rsrc) * DIM + kk + ksrc,
              As + wave * 512);
    __syncthreads();
    s16x8 fa[4], fb[4];
#pragma unroll
    for (int m = 0; m < 4; ++m)
      fa[m] = ldfrag(&As[(m * 16 + (lane & 15)) * 32 + (lane >> 4) * 8]);
#pragma unroll
    for (int n = 0; n < 4; ++n)
      fb[n] = ldfrag(
          &Bs[(wave * 64 + n * 16 + (lane & 15)) * 32 + (lane >> 4) * 8]);
#pragma unroll
    for (int m = 0; m < 4; ++m)
#pragma unroll
      for (int n = 0; n < 4; ++n)
        acc[m][n] = __builtin_amdgcn_mfma_f32_16x16x32_bf16(fa[m], fb[n],
                                                            acc[m][n], 0, 0, 0);
    __syncthreads();
  }
  const float s = *scale_ptr;
  const int rq = lane >> 4, c_ = lane & 15;
#pragma unroll
  for (int n = 0; n < 4; ++n) {
    const int col = wave * 64 + n * 16 + c_;
    const float bc = bias[col];
    const int cbase = col >> 3, wof = col & 7;
#pragma unroll
    for (int m = 0; m < 4; ++m)
#pragma unroll
      for (int j = 0; j < 4; ++j) {
        const int row = m * 16 + rq * 4 + j;
        const int cS = cbase ^ (((row >> 2) & 3) << 1);
        smem[row * 512 + cS * 8 + wof] = pack1bf(s * tanh_fast(acc[m][n][j] + bc));
      }
  }
  __syncthreads();
  const int prow = tid >> 3, sub = tid & 7;
  const int rq2 = ((prow >> 2) & 3) << 1;
  const u16* xrow = XB + (size_t)(row0 + prow) * DIM;
  const u16* x0row = X0B + (size_t)(row0 + prow) * DIM;
  float ss = 0.f;
#pragma unroll
  for (int i = 0; i < 8; ++i) {
    const int c = sub + 8 * i;
    uint4 xb = *(const uint4*)(xrow + c * 8);
    uint4 x0 = *(const uint4*)(x0row + c * 8);
    uint4 uu = *(const uint4*)&smem[prow * 512 + (c ^ rq2) * 8];
    float t0 = 0.8f * (bflo(xb.x) + bflo(uu.x)) + 0.2f * bflo(x0.x);
    float t1 = 0.8f * (bfhi(xb.x) + bfhi(uu.x)) + 0.2f * bfhi(x0.x);
    float t2 = 0.8f * (bflo(xb.y) + bflo(uu.y)) + 0.2f * bflo(x0.y);
    float t3 = 0.8f * (bfhi(xb.y) + bfhi(uu.y)) + 0.2f * bfhi(x0.y);
    float t4 = 0.8f * (bflo(xb.z) + bflo(uu.z)) + 0.2f * bflo(x0.z);
    float t5 = 0.8f * (bfhi(xb.z) + bfhi(uu.z)) + 0.2f * bfhi(x0.z);
    float t6 = 0.8f * (bflo(xb.w) + bflo(uu.w)) + 0.2f * bflo(x0.w);
    float t7 = 0.8f * (bfhi(xb.w) + bfhi(uu.w)) + 0.2f * bfhi(x0.w);
    ss += t0 * t0 + t1 * t1 + t2 * t2 + t3 * t3 + t4 * t4 + t5 * t5 +
          t6 * t6 + t7 * t7;
    uint4 tp;
    tp.x = pack2bf(t0, t1); tp.y = pack2bf(t2, t3);
    tp.z = pack2bf(t4, t5); tp.w = pack2bf(t6, t7);
    *(uint4*)&smem[prow * 512 + (c ^ rq2) * 8] = tp;
  }
#pragma unroll
  for (int off = 4; off >= 1; off >>= 1) ss += __shfl_xor(ss, off);
  const float inv = 1.f / fmaxf(sqrtf(ss), 1e-12f);
  u16* orow = XB + (size_t)(row0 + prow) * DIM;
#pragma unroll
  for (int i = 0; i < 8; ++i) {
    const int c = sub + 8 * i;
    uint4 tp = *(const uint4*)&smem[prow * 512 + (c ^ rq2) * 8];
    uint4 r;
    r.x = pack2bf(bflo(tp.x) * inv, bfhi(tp.x) * inv);
    r.y = pack2bf(bflo(tp.y) * inv, bfhi(tp.y) * inv);
    r.z = pack2bf(bflo(tp.z) * inv, bfhi(tp.z) * inv);
    r.w = pack2bf(bflo(tp.w) * inv, bfhi(tp.w) * inv);
    *(uint4*)(orow + c * 8) = r;
  }
}

// Fused prototype branch: per-episode block (64 thr). LDS-stage bf16 P,
// 20x20 gram via MFMA, per-row serial top-5 + softmax, LDS-gather message.
__global__ __launch_bounds__(64) void p_branch_kernel(
    const u16* __restrict__ PB, u16* __restrict__ PMSGB) {
  const int b = blockIdx.x;
  const int lane = threadIdx.x;
  __shared__ __align__(16) u16 Pl[32][520];
  __shared__ float Gl[NWAYS][NWAYS];
  __shared__ float Wl[NWAYS][KNEI];
  __shared__ int Il[NWAYS][KNEI];
  const u16* Pb = PB + (size_t)b * NWAYS * DIM;
  for (int c = lane; c < 32 * 64; c += 64) {
    int m = c >> 6, ko = (c & 63) * 8;
    uint4 v = {0, 0, 0, 0};
    if (m < NWAYS) v = *(const uint4*)(Pb + (size_t)m * DIM + ko);
    *(uint4*)&Pl[m][ko] = v;
  }
  __syncthreads();
  f32x4 acc[2][2];
#pragma unroll
  for (int m = 0; m < 2; ++m)
#pragma unroll
    for (int n = 0; n < 2; ++n) acc[m][n] = (f32x4){0.f, 0.f, 0.f, 0.f};
  for (int kk = 0; kk < DIM; kk += 32) {
    s16x8 f[2];
#pragma unroll
    for (int m = 0; m < 2; ++m)
      f[m] = ldfrag(&Pl[m * 16 + (lane & 15)][kk + (lane >> 4) * 8]);
#pragma unroll
    for (int m = 0; m < 2; ++m)
#pragma unroll
      for (int n = 0; n < 2; ++n)
        acc[m][n] = __builtin_amdgcn_mfma_f32_16x16x32_bf16(f[m], f[n],
                                                            acc[m][n], 0, 0, 0);
  }
  const int r_ = (lane >> 4) * 4, c_ = lane & 15;
#pragma unroll
  for (int m = 0; m < 2; ++m)
#pragma unroll
    for (int n = 0; n < 2; ++n)
#pragma unroll
      for (int j = 0; j < 4; ++j) {
        int r = m * 16 + r_ + j, c = n * 16 + c_;
        if (r < NWAYS && c < NWAYS) Gl[r][c] = acc[m][n][j];
      }
  __syncthreads();
  if (lane < NWAYS) {
    float sims[NWAYS];
#pragma unroll
    for (int m = 0; m < NWAYS; ++m) sims[m] = Gl[lane][m];
    float topv[KNEI];
    int topi[KNEI];
#pragma unroll
    for (int t = 0; t < KNEI; ++t) {
      float bv = -INFINITY;
      int bi = 0;
#pragma unroll
      for (int m = 0; m < NWAYS; ++m)
        if (sims[m] > bv) { bv = sims[m]; bi = m; }
      sims[bi] = -INFINITY;
      topv[t] = bv;
      topi[t] = bi;
    }
    float w[KNEI], wsum = 0.f;
#pragma unroll
    for (int t = 0; t < KNEI; ++t) {
      w[t] = __expf((topv[t] - topv[0]) * TAU_INV);
      wsum += w[t];
    }
    const float invs = 1.f / wsum;
#pragma unroll
    for (int t = 0; t < KNEI; ++t) {
      Wl[lane][t] = w[t] * invs;
      Il[lane][t] = topi[t];
    }
  }
  __syncthreads();
  u16* outp = PMSGB + (size_t)b * NWAYS * DIM;
#pragma unroll 4
  for (int n = 0; n < NWAYS; ++n) {
    float a8[8] = {0.f, 0.f, 0.f, 0.f, 0.f, 0.f, 0.f, 0.f};
#pragma unroll
    for (int t = 0; t < KNEI; ++t) {
      const float w = Wl[n][t];
      uint4 v = *(const uint4*)&Pl[Il[n][t]][8 * lane];
      a8[0] += w * bflo(v.x); a8[1] += w * bfhi(v.x);
      a8[2] += w * bflo(v.y); a8[3] += w * bfhi(v.y);
      a8[4] += w * bflo(v.z); a8[5] += w * bfhi(v.z);
      a8[6] += w * bflo(v.w); a8[7] += w * bfhi(v.w);
    }
    uint4 r;
    r.x = pack2bf(a8[0], a8[1]);
    r.y = pack2bf(a8[2], a8[3]);
    r.z = pack2bf(a8[4], a8[5]);
    r.w = pack2bf(a8[6], a8[7]);
    *(uint4*)(outp + (size_t)n * DIM + 8 * lane) = r;
  }
}

// Fully fused guidance tail, per-episode block (512 thr = 8 waves):
//   Pa = l2n(alpha*P + (1-alpha)*l2n(mean support V))  -> LDS only
//   per V row: s = V·Pa^T, softmax, g = soft·Pa, y = l2n(beta*V+(1-beta)*g)
//   query rows: logits = 5*(y·Pa^T), exact serial argmax/CE on lane 0
// Replaces vcpa + sims + gram + softce + vupdate (and their HBM buffers).
__global__ __launch_bounds__(512) void episode_tail_kernel(
    u16* __restrict__ VB, const u16* __restrict__ PB,
    const int* __restrict__ qy, const float* __restrict__ alpha_ptr,
    const float* __restrict__ beta_ptr, float* __restrict__ accum,
    int is_last) {
  const int b = blockIdx.x;
  const int tid = threadIdx.x, wave = tid >> 6, lane = tid & 63;
  __shared__ __align__(16) u16 palds[NWAYS * PALD];  // 20.8 KB
  __shared__ float red[16];
  const u16* Vb0 = VB + (size_t)b * NT * DIM;
  const float alpha = *alpha_ptr, oma = 1.f - alpha;
  const float beta = *beta_ptr, omb = 1.f - beta;
  // step 1: Pa rows (vcpa) into LDS
  for (int n = wave; n < NWAYS; n += 8) {
    const u16* base = Vb0 + (size_t)n * KSHOT * DIM;
    float a8[8] = {0.f, 0.f, 0.f, 0.f, 0.f, 0.f, 0.f, 0.f};
#pragma unroll
    for (int k = 0; k < KSHOT; ++k) {
      uint4 v = *(const uint4*)(base + (size_t)k * DIM + 8 * lane);
      a8[0] += bflo(v.x); a8[1] += bfhi(v.x);
      a8[2] += bflo(v.y); a8[3] += bfhi(v.y);
      a8[4] += bflo(v.z); a8[5] += bfhi(v.z);
      a8[6] += bflo(v.w); a8[7] += bfhi(v.w);
    }
    float ss = 0.f;
#pragma unroll
    for (int t = 0; t < 8; ++t) ss += a8[t] * a8[t];
    ss = waveReduceSum(ss);
    const float inv = 1.f / fmaxf(sqrtf(ss), 1e-12f);  // mean cancels in l2n
    {
      uint4 p = *(const uint4*)(PB + ((size_t)b * NWAYS + n) * DIM + 8 * lane);
      a8[0] = alpha * bflo(p.x) + oma * a8[0] * inv;
      a8[1] = alpha * bfhi(p.x) + oma * a8[1] * inv;
      a8[2] = alpha * bflo(p.y) + oma * a8[2] * inv;
      a8[3] = alpha * bfhi(p.y) + oma * a8[3] * inv;
      a8[4] = alpha * bflo(p.z) + oma * a8[4] * inv;
      a8[5] = alpha * bfhi(p.z) + oma * a8[5] * inv;
      a8[6] = alpha * bfhi(p.w) * 0.f + alpha * bflo(p.w) + oma * a8[6] * inv;
      a8[7] = alpha * bfhi(p.w) + oma * a8[7] * inv;
    }
    float s2 = 0.f;
#pragma unroll
    for (int t = 0; t < 8; ++t) s2 += a8[t] * a8[t];
    s2 = waveReduceSum(s2);
    const float inv2 = 1.f / fmaxf(sqrtf(s2), 1e-12f);
    uint4 r;
    r.x = pack2bf(a8[0] * inv2, a8[1] * inv2);
    r.y = pack2bf(a8[2] * inv2, a8[3] * inv2);
    r.z = pack2bf(a8[4] * inv2, a8[5] * inv2);
    r.w = pack2bf(a8[6] * inv2, a8[7] * inv2);
    *(uint4*)&palds[n * PALD + 8 * lane] = r;
  }
  __syncthreads();
  // step 2: per-row guidance update (+ CE for query rows)
  float ce_acc = 0.f, ac_acc = 0.f;
  for (int row = wave; row < NT; row += 8) {
    u16* vrow = VB + ((size_t)b * NT + row) * DIM;
    uint4 v4 = *(const uint4*)(vrow + 8 * lane);
    float v[8] = {bflo(v4.x), bfhi(v4.x), bflo(v4.y), bfhi(v4.y),
                  bflo(v4.z), bfhi(v4.z), bflo(v4.w), bfhi(v4.w)};
    float s[NWAYS];
#pragma unroll
    for (int m = 0; m < NWAYS; ++m) {
      uint4 p = *(const uint4*)&palds[m * PALD + 8 * lane];
      s[m] = v[0] * bflo(p.x) + v[1] * bfhi(p.x) + v[2] * bflo(p.y) +
             v[3] * bfhi(p.y) + v[4] * bflo(p.z) + v[5] * bfhi(p.z) +
             v[6] * bflo(p.w) + v[7] * bfhi(p.w);
    }
#pragma unroll
    for (int off = 32; off >= 1; off >>= 1)
#pragma unroll
      for (int m = 0; m < NWAYS; ++m) s[m] += __shfl_xor(s[m], off);
    float mx = s[0];
#pragma unroll
    for (int m = 1; m < NWAYS; ++m) mx = fmaxf(mx, s[m]);
    float e[NWAYS], wsum = 0.f;
#pragma unroll
    for (int m = 0; m < NWAYS; ++m) {
      e[m] = __expf((s[m] - mx) * TAU_INV);
      wsum += e[m];
    }
    const float ci = omb / wsum;
    float t8[8] = {0.f, 0.f, 0.f, 0.f, 0.f, 0.f, 0.f, 0.f};
#pragma unroll
    for (int m = 0; m < NWAYS; ++m) {
      uint4 p = *(const uint4*)&palds[m * PALD + 8 * lane];
      t8[0] += e[m] * bflo(p.x); t8[1] += e[m] * bfhi(p.x);
      t8[2] += e[m] * bflo(p.y); t8[3] += e[m] * bfhi(p.y);
      t8[4] += e[m] * bflo(p.z); t8[5] += e[m] * bfhi(p.z);
      t8[6] += e[m] * bflo(p.w); t8[7] += e[m] * bfhi(p.w);
    }
    float ss = 0.f;
#pragma unroll
    for (int t = 0; t < 8; ++t) {
      t8[t] = beta * v[t] + ci * t8[t];
      ss += t8[t] * t8[t];
    }
    ss = waveReduceSum(ss);
    const float inv = 1.f / fmaxf(sqrtf(ss), 1e-12f);
    float y[8];
#pragma unroll
    for (int t = 0; t < 8; ++t) y[t] = t8[t] * inv;
    uint4 r;
    r.x = pack2bf(y[0], y[1]); r.y = pack2bf(y[2], y[3]);
    r.z = pack2bf(y[4], y[5]); r.w = pack2bf(y[6], y[7]);
    *(uint4*)(vrow + 8 * lane) = r;
    if (row >= NKS) {
      float lg[NWAYS];
#pragma unroll
      for (int m = 0; m < NWAYS; ++m) {
        uint4 p = *(const uint4*)&palds[m * PALD + 8 * lane];
        lg[m] = y[0] * bflo(p.x) + y[1] * bfhi(p.x) + y[2] * bflo(p.y) +
                y[3] * bfhi(p.y) + y[4] * bflo(p.z) + y[5] * bfhi(p.z) +
                y[6] * bflo(p.w) + y[7] * bfhi(p.w);
      }
#pragma unroll
      for (int off = 32; off >= 1; off >>= 1)
#pragma unroll
        for (int m = 0; m < NWAYS; ++m) lg[m] += __shfl_xor(lg[m], off);
      if (lane == 0) {
        const int yt = qy[b * NQ + (row - NKS)];
#pragma unroll
        for (int m = 0; m < NWAYS; ++m) lg[m] *= LOGIT_SCALE;
        float m2 = lg[0];
        int am = 0;
#pragma unroll
        for (int m = 1; m < NWAYS; ++m)
          if (lg[m] > m2) { m2 = lg[m]; am = m; }
        float se = 0.f;
#pragma unroll
        for (int m = 0; m < NWAYS; ++m) se += __expf(lg[m] - m2);
        ce_acc += m2 + __logf(se) - lg[yt];
        ac_acc += (am == yt) ? 1.f : 0.f;
      }
    }
  }
  if (lane == 0) {
    red[wave] = ce_acc;
    red[8 + wave] = ac_acc;
  }
  __syncthreads();
  if (tid == 0) {
    float ce = 0.f, ac = 0.f;
#pragma unroll
    for (int w8 = 0; w8 < 8; ++w8) {
      ce += red[w8];
      ac += red[8 + w8];
    }
    atomicAdd(&accum[0], ce);
    if (is_last) atomicAdd(&accum[1], ac);
  }
}

__global__ void finalize_kernel(const float* __restrict__ acc,
                                float* __restrict__ out) {
  out[0] = acc[0] / (float)(NLAYERS * B_EP * NQ);
  out[1] = acc[1] / (float)(B_EP * NQ);
}

extern "C" void kernel_launch(void* const* d_in, const int* in_sizes, int n_in,
                              void* d_out, int out_size, void* d_ws,
                              size_t ws_size, hipStream_t stream) {
  const float* V_feat = (const float*)d_in[0];
  const float* P_feat = (const float*)d_in[1];
  const int* query_y = (const int*)d_in[2];
  const float* igb_W = (const float*)d_in[3];
  const float* igb_b = (const float*)d_in[4];
  const float* igb_s = (const float*)d_in[5];
  const float* pgb_W = (const float*)d_in[6];
  const float* pgb_b = (const float*)d_in[7];
  const float* pgb_s = (const float*)d_in[8];
  const float* alpha = (const float*)d_in[9];
  const float* beta = (const float*)d_in[10];
  float* out = (float*)d_out;

  float* ws = (float*)d_ws;
  const size_t vsz = (size_t)B_EP * NT * DIM;       // 22,937,600
  const size_t psz = (size_t)B_EP * NWAYS * DIM;    // 2,621,440
  const size_t wsz = (size_t)NLAYERS * DIM * DIM;   // 1,048,576
  float* ACC = ws;
  u16* VB = (u16*)(ws + 16);
  u16* V0B = VB + vsz;
  u16* MSGB = V0B + vsz;
  u16* PB = MSGB + vsz;
  u16* P0B = PB + psz;
  u16* PMSGB = P0B + psz;
  u16* WB = PMSGB + psz;
  u16* WPB = WB + wsz;

  init_accum_kernel<<<1, 64, 0, stream>>>(ACC);
  l2n_init_kernel<<<B_EP * NT, 64, 0, stream>>>(V_feat, VB, V0B);
  l2n_init_kernel<<<B_EP * NWAYS, 64, 0, stream>>>(P_feat, PB, P0B);
  cvt_bf16_kernel<<<(int)(wsz / 8 / 256), 256, 0, stream>>>(igb_W, WB,
                                                            (int)(wsz / 8));
  cvt_bf16_kernel<<<(int)(wsz / 8 / 256), 256, 0, stream>>>(pgb_W, WPB,
                                                            (int)(wsz / 8));

  for (int i = 0; i < NLAYERS; ++i) {
    sim_topk_msg_kernel<<<B_EP, 576, 0, stream>>>(VB, MSGB);
    gemm_fused_kernel<<<B_EP * NT / 64, 512, 0, stream>>>(
        MSGB, WB + (size_t)i * DIM * DIM, igb_b + (size_t)i * DIM, igb_s + i,
        VB, V0B);

    p_branch_kernel<<<B_EP, 64, 0, stream>>>(PB, PMSGB);
    gemm_fused_kernel<<<B_EP * NWAYS / 64, 512, 0, stream>>>(
        PMSGB, WPB + (size_t)i * DIM * DIM, pgb_b + (size_t)i * DIM, pgb_s + i,
        PB, P0B);

    episode_tail_kernel<<<B_EP, 512, 0, stream>>>(
        VB, PB, query_y, alpha, beta, ACC, (i == NLAYERS - 1) ? 1 : 0);
  }
  finalize_kernel<<<1, 1, 0, stream>>>(ACC, out);
}